// Round 9
// baseline (20419.295 us; speedup 1.0000x reference)
//
#include <hip/hip_runtime.h>

#define T_LEN 256
#define B_SZ  64
#define H_SZ  1024
#define G4H   4096
#define HB    (B_SZ * H_SZ)              // 65536
#define NBLK  256
#define RING_SLOTS (T_LEN + 1)           // slot t = h(t); slot T_LEN = h(-1)

typedef __attribute__((ext_vector_type(8))) short short8;
typedef __attribute__((ext_vector_type(4))) float float4_;
typedef __attribute__((ext_vector_type(4))) unsigned int uint4_;
typedef __attribute__((ext_vector_type(8))) unsigned int uint8_;

__device__ __forceinline__ unsigned short bf16_rne(float x) {
  unsigned u = __builtin_bit_cast(unsigned, x);
  unsigned r = u + 0x7FFFu + ((u >> 16) & 1u);
  return (unsigned short)(r >> 16);
}
__device__ __forceinline__ float bf16_to_f32(unsigned short s) {
  unsigned u = ((unsigned)s) << 16;
  return __builtin_bit_cast(float, u);
}

// ---------- prep: x fp32 -> packed split-bf16 (hi | lo<<16) dwords ----------
__global__ __launch_bounds__(256)
void pack_x(const float* __restrict__ src, unsigned* __restrict__ dst) {
  const size_t i = ((size_t)blockIdx.x * 256 + threadIdx.x) * 4;
  float4_ v = *(const float4_*)(src + i);
  uint4_ o;
  #pragma unroll
  for (int j = 0; j < 4; ++j) {
    const unsigned short h = bf16_rne(v[j]);
    const unsigned short l = bf16_rne(v[j] - bf16_to_f32(h));
    o[j] = (unsigned)h | ((unsigned)l << 16);
  }
  *(uint4_*)(dst + i) = o;
}

// ---------- prep: h0 -> bf16 ring slot T_LEN (t = -1) + zero flags ----------
__global__ __launch_bounds__(256)
void init_h(const float* __restrict__ h0, unsigned short* __restrict__ ringb,
            unsigned* __restrict__ bar) {
  if (blockIdx.x == 0) {
    #pragma unroll
    for (int j = 0; j < 4; ++j) bar[threadIdx.x * 4 + j] = 0u;
  }
  const int e0 = (blockIdx.x * 256 + threadIdx.x) * 4;
  #pragma unroll
  for (int j = 0; j < 4; ++j) {
    const int e = e0 + j;                 // [2][B][H] = 131072 elems
    const int l = e >> 16;
    const int rem = e & (HB - 1);
    ringb[((size_t)l * RING_SLOTS + T_LEN) * HB + rem] = bf16_rne(h0[e]);
  }
}

// poll ALL 128 producer flags of a layer in one round (2 loads/lane)
__device__ __forceinline__ void poll_all128(const unsigned* f, unsigned v,
                                            int lane) {
  for (;;) {
    const unsigned a = __hip_atomic_load(f + lane, __ATOMIC_RELAXED,
                                         __HIP_MEMORY_SCOPE_AGENT);
    const unsigned b = __hip_atomic_load(f + 64 + lane, __ATOMIC_RELAXED,
                                         __HIP_MEMORY_SCOPE_AGENT);
    if (__all((int)(a >= v && b >= v))) return;
    __builtin_amdgcn_s_sleep(1);
  }
}
// poll n (<64) contiguous flags; lanes >= n pass vacuously
__device__ __forceinline__ void poll_n(const unsigned* f, int n, unsigned v,
                                       int lane) {
  for (;;) {
    unsigned s = 0xFFFFFFFFu;
    if (lane < n)
      s = __hip_atomic_load(f + lane, __ATOMIC_RELAXED,
                            __HIP_MEMORY_SCOPE_AGENT);
    if (__all((int)(s >= v))) return;
    __builtin_amdgcn_s_sleep(1);
  }
}

// ---------- persistent LSTM: single-critical-wave step ----------
// Per WG (l, cb): wave 0 alone runs the full-K recurrent GEMM (h-weights in
// LDS), assembles gates in-register via 2 shuffle-exchange rounds, fuses the
// elementwise, stores h(t) (4B packed agent atomics), drains, flags. Waves
// 1-7 compute the x-side for t+1 (7-way K-split, weights in regs) and
// ds_add_f32 into a double-buffered LDS gate tile. ONE barrier per step.
// Flags: bar[l*128+cb] = t+1 after step t (one per producer WG).
__global__ __launch_bounds__(512, 1)
void lstm_persist(const unsigned* __restrict__ xp,     // packed x [T][B][H]
                  const float* __restrict__ c0_in,
                  const float* __restrict__ Wih,       // fp32 [L][4H][H]
                  const float* __restrict__ Whh,
                  const float* __restrict__ bih,
                  const float* __restrict__ bhh,
                  unsigned short* __restrict__ ringb,  // [L][257][B][H] bf16
                  float* __restrict__ out,
                  unsigned* __restrict__ bar)          // [2][128] flags
{
  const int wg   = blockIdx.x;
  const int tid  = threadIdx.x;
  const int lane = tid & 63;
  const int wave = tid >> 6;

  const int layer = wg >> 7;
  const int cb    = wg & 127;
  const int nn    = lane & 15;
  const int quad  = lane >> 4;
  const int hc    = nn & 7;
  const int hi8   = nn >> 3;
  const int hi1   = nn & 1;
  const int hc2   = nn & 6;            // even hcol of this lane's pair

  __shared__ short8 whh[2][32][2][64];   // [pl][kb][nt][lane] = 128 KB
  __shared__ float  xtile[2][64][36];    // 18 KB, dbuf by t&1

  int growA[2];
  #pragma unroll
  for (int nt = 0; nt < 2; ++nt) {
    const int q = nt * 2 + hi8;
    growA[nt] = q * H_SZ + cb * 8 + hc;
  }

  // ---- one-time: Whh -> split-bf16 fragments in LDS (all waves, 4 kb each)
  #pragma unroll
  for (int i = 0; i < 4; ++i) {
    const int kbg = wave * 4 + i;
    #pragma unroll
    for (int nt = 0; nt < 2; ++nt) {
      const float* p = Whh + ((size_t)layer * G4H + growA[nt]) * H_SZ +
                       kbg * 32 + quad * 8;
      short8 hi, lo;
      #pragma unroll
      for (int j = 0; j < 8; ++j) {
        const float v = p[j];
        const unsigned short h = bf16_rne(v);
        hi[j] = (short)h;
        lo[j] = (short)bf16_rne(v - bf16_to_f32(h));
      }
      whh[0][kbg][nt][lane] = hi;
      whh[1][kbg][nt][lane] = lo;
    }
  }

  // ---- one-time: Wih chunk -> registers (waves 1..7; 7-way kb split)
  short8 wx[2][2][5];                    // [pl][nt][i]
  int kbstart = 0, nkb = 0;
  if (wave >= 1) {
    const int sw = wave - 1;
    kbstart = (sw < 4) ? sw * 5 : 20 + (sw - 4) * 4;
    nkb = (sw < 4) ? 5 : 4;
    #pragma unroll
    for (int i = 0; i < 5; ++i) if (i < nkb) {
      #pragma unroll
      for (int nt = 0; nt < 2; ++nt) {
        const float* p = Wih + ((size_t)layer * G4H + growA[nt]) * H_SZ +
                         (kbstart + i) * 32 + quad * 8;
        short8 hi, lo;
        #pragma unroll
        for (int j = 0; j < 8; ++j) {
          const float v = p[j];
          const unsigned short h = bf16_rne(v);
          hi[j] = (short)h;
          lo[j] = (short)bf16_rne(v - bf16_to_f32(h));
        }
        wx[0][nt][i] = hi;
        wx[1][nt][i] = lo;
      }
    }
  }

  // ---- wave-0 elementwise constants
  const int hcol0 = cb * 8 + hc2;
  float bias[2][4];
  #pragma unroll
  for (int s = 0; s < 2; ++s)
    #pragma unroll
    for (int q = 0; q < 4; ++q)
      bias[s][q] = bih[layer * G4H + q * H_SZ + hcol0 + s] +
                   bhh[layer * G4H + q * H_SZ + hcol0 + s];

  unsigned*       slotp = bar + layer * 128 + cb;
  const unsigned* fown  = bar + layer * 128;
  const unsigned* fl0   = bar;
  const unsigned short* ring_own = ringb + (size_t)layer * RING_SLOTS * HB;

  float creg[2][4];
  #pragma unroll
  for (int s = 0; s < 2; ++s)
    #pragma unroll
    for (int r = 0; r < 4; ++r) creg[s][r] = 0.f;

  // ---- shadow x-GEMM + LDS atomic accumulate (waves 1..7)
  auto do_shadow = [&](int tt, int buf) {
    float4_ as[4][2];
    #pragma unroll
    for (int m = 0; m < 4; ++m)
      #pragma unroll
      for (int nt = 0; nt < 2; ++nt)
        as[m][nt] = float4_{0.f, 0.f, 0.f, 0.f};
    if (layer == 0) {
      const unsigned* src = xp + (size_t)tt * HB;
      #pragma unroll
      for (int i = 0; i < 5; ++i) if (i < nkb) {
        const int k0 = (kbstart + i) * 32 + quad * 8;
        #pragma unroll
        for (int m = 0; m < 4; ++m) {
          const uint8_ u = *(const uint8_*)(src + (size_t)(m * 16 + nn) * H_SZ + k0);
          uint4_ h4, l4;
          #pragma unroll
          for (int r = 0; r < 4; ++r) {
            h4[r] = __builtin_amdgcn_perm(u[2 * r + 1], u[2 * r], 0x05040100u);
            l4[r] = __builtin_amdgcn_perm(u[2 * r + 1], u[2 * r], 0x07060302u);
          }
          const short8 ah = __builtin_bit_cast(short8, h4);
          const short8 al = __builtin_bit_cast(short8, l4);
          #pragma unroll
          for (int nt = 0; nt < 2; ++nt) {
            as[m][nt] = __builtin_amdgcn_mfma_f32_16x16x32_bf16(ah, wx[0][nt][i], as[m][nt], 0, 0, 0);
            as[m][nt] = __builtin_amdgcn_mfma_f32_16x16x32_bf16(al, wx[0][nt][i], as[m][nt], 0, 0, 0);
            as[m][nt] = __builtin_amdgcn_mfma_f32_16x16x32_bf16(ah, wx[1][nt][i], as[m][nt], 0, 0, 0);
          }
        }
      }
    } else {
      poll_n(fl0 + kbstart * 4, nkb * 4, (unsigned)(tt + 1), lane);
      asm volatile("" ::: "memory");
      const unsigned short* src = ringb + (size_t)tt * HB;  // layer-0 slot tt
      #pragma unroll
      for (int i = 0; i < 5; ++i) if (i < nkb) {
        const int k0 = (kbstart + i) * 32 + quad * 8;
        #pragma unroll
        for (int m = 0; m < 4; ++m) {
          const short8 a = *(const short8*)(src + (size_t)(m * 16 + nn) * H_SZ + k0);
          #pragma unroll
          for (int nt = 0; nt < 2; ++nt) {
            as[m][nt] = __builtin_amdgcn_mfma_f32_16x16x32_bf16(a, wx[0][nt][i], as[m][nt], 0, 0, 0);
            as[m][nt] = __builtin_amdgcn_mfma_f32_16x16x32_bf16(a, wx[1][nt][i], as[m][nt], 0, 0, 0);
          }
        }
      }
    }
    #pragma unroll
    for (int m = 0; m < 4; ++m)
      #pragma unroll
      for (int nt = 0; nt < 2; ++nt)
        #pragma unroll
        for (int r = 0; r < 4; ++r)
          atomicAdd(&xtile[buf][m * 16 + quad * 4 + r][hc * 4 + nt * 2 + hi8],
                    as[m][nt][r]);
  };

  // ---- prologue: zero xtile, fill xtile[0] with x(0)
  {
    float4_* zb = (float4_*)&xtile[0][0][0];
    #pragma unroll
    for (int i = 0; i < 3; ++i) {
      const int idx = i * 512 + tid;
      if (idx < 2 * 64 * 36 / 4) zb[idx] = float4_{0.f, 0.f, 0.f, 0.f};
    }
  }
  __syncthreads();
  if (wave >= 1) do_shadow(0, 0);
  __syncthreads();

  #pragma unroll 1
  for (int t = 0; t < T_LEN; ++t) {
    if (wave == 0) {
      // ---- wait: all 128 own-layer producers done with step t-1
      if (t > 0) {
        poll_all128(fown, (unsigned)t, lane);
        asm volatile("" ::: "memory");
      }
      // ---- full-K recurrent GEMM, streaming (512 MFMA, one wave)
      const unsigned short* hsrc =
          ring_own + (size_t)(t ? t - 1 : T_LEN) * HB;
      float4_ acc[4][2];
      #pragma unroll
      for (int m = 0; m < 4; ++m)
        #pragma unroll
        for (int nt = 0; nt < 2; ++nt)
          acc[m][nt] = float4_{0.f, 0.f, 0.f, 0.f};
      for (int ck = 0; ck < 8; ++ck) {
        #pragma unroll
        for (int kb = 0; kb < 4; ++kb) {
          const int kbg = ck * 4 + kb;
          const int k0 = kbg * 32 + quad * 8;
          short8 a[4];
          #pragma unroll
          for (int m = 0; m < 4; ++m)
            a[m] = *(const short8*)(hsrc + (size_t)(m * 16 + nn) * H_SZ + k0);
          const short8 bh0 = whh[0][kbg][0][lane];
          const short8 bh1 = whh[0][kbg][1][lane];
          const short8 bl0 = whh[1][kbg][0][lane];
          const short8 bl1 = whh[1][kbg][1][lane];
          #pragma unroll
          for (int m = 0; m < 4; ++m) {
            acc[m][0] = __builtin_amdgcn_mfma_f32_16x16x32_bf16(a[m], bh0, acc[m][0], 0, 0, 0);
            acc[m][0] = __builtin_amdgcn_mfma_f32_16x16x32_bf16(a[m], bl0, acc[m][0], 0, 0, 0);
            acc[m][1] = __builtin_amdgcn_mfma_f32_16x16x32_bf16(a[m], bh1, acc[m][1], 0, 0, 0);
            acc[m][1] = __builtin_amdgcn_mfma_f32_16x16x32_bf16(a[m], bl1, acc[m][1], 0, 0, 0);
          }
        }
      }
      // ---- exchange 1 (xor 8): merge gate split; lane keeps its 2 m-tiles
      float g[2][4][4];   // [mm][q][r]
      #pragma unroll
      for (int mm = 0; mm < 2; ++mm)
        #pragma unroll
        for (int j = 0; j < 2; ++j)
          #pragma unroll
          for (int r = 0; r < 4; ++r) {
            const float send = acc[hi8 ? mm : 2 + mm][j][r];
            const float rec = __shfl_xor(send, 8);
            g[mm][2 * j + hi8][r]     = acc[hi8 * 2 + mm][j][r];
            g[mm][2 * j + 1 - hi8][r] = rec;
          }
      // ---- exchange 2 (xor 1): pair adjacent hcols; lane keeps 1 m-tile
      float h2[2][4][4];  // [s][q][r], s = hcol parity within pair
      #pragma unroll
      for (int q = 0; q < 4; ++q)
        #pragma unroll
        for (int r = 0; r < 4; ++r) {
          const float send = g[1 - hi1][q][r];
          const float rec = __shfl_xor(send, 1);
          h2[hi1][q][r]     = g[hi1][q][r];
          h2[1 - hi1][q][r] = rec;
        }
      // ---- fused elementwise: 4 batches x 2 hcols per lane
      const int mt = 2 * hi8 + hi1;
      #pragma unroll
      for (int r = 0; r < 4; ++r) {
        const int b = mt * 16 + quad * 4 + r;
        float hn[2];
        #pragma unroll
        for (int s = 0; s < 2; ++s) {
          const float4_ xt = *(const float4_*)&xtile[t & 1][b][(hc2 + s) * 4];
          const float g0 = h2[s][0][r] + xt[0] + bias[s][0];
          const float g1 = h2[s][1][r] + xt[1] + bias[s][1];
          const float g2 = h2[s][2][r] + xt[2] + bias[s][2];
          const float g3 = h2[s][3][r] + xt[3] + bias[s][3];
          const float cprev = (t == 0)
              ? c0_in[(size_t)layer * HB + (size_t)b * H_SZ + hcol0 + s]
              : creg[s][r];
          const float ig = 1.f / (1.f + __expf(-g0));
          const float fg = 1.f / (1.f + __expf(-g1));
          const float gg = tanhf(g2);
          const float og = 1.f / (1.f + __expf(-g3));
          const float cn = fg * cprev + ig * gg;
          hn[s] = og * tanhf(cn);
          creg[s][r] = cn;
        }
        const size_t ridx = ((size_t)layer * RING_SLOTS + t) * HB +
                            (size_t)b * H_SZ + hcol0;      // even -> 4B align
        const unsigned pk = (unsigned)bf16_rne(hn[0]) |
                            ((unsigned)bf16_rne(hn[1]) << 16);
        __hip_atomic_store((unsigned*)(ringb + ridx), pk,
                           __ATOMIC_RELAXED, __HIP_MEMORY_SCOPE_AGENT);
        if (layer == 1 && t == T_LEN - 1) {
          out[(size_t)b * H_SZ + hcol0]     = hn[0];
          out[(size_t)b * H_SZ + hcol0 + 1] = hn[1];
        }
      }
      // ---- re-zero the consumed xtile buffer (for shadow at t+1)
      {
        float4_* zb = (float4_*)&xtile[t & 1][0][0];
        #pragma unroll
        for (int i = 0; i < 9; ++i)
          zb[i * 64 + lane] = float4_{0.f, 0.f, 0.f, 0.f};
      }
      // ---- drain ring stores, then flag
      asm volatile("s_waitcnt vmcnt(0)" ::: "memory");
      if (lane == 0)
        __hip_atomic_store(slotp, (unsigned)(t + 1),
                           __ATOMIC_RELAXED, __HIP_MEMORY_SCOPE_AGENT);
    } else if (t < T_LEN - 1) {
      // ---- shadow: x-side for t+1 into xtile[(t+1)&1]
      do_shadow(t + 1, (t + 1) & 1);
    }
    __syncthreads();   // the ONLY barrier per step
  }
}

extern "C" void kernel_launch(void* const* d_in, const int* in_sizes, int n_in,
                              void* d_out, int out_size, void* d_ws, size_t ws_size,
                              hipStream_t stream) {
  (void)in_sizes; (void)n_in; (void)out_size; (void)ws_size;
  const float* x   = (const float*)d_in[0];
  const float* h0  = (const float*)d_in[1];
  const float* c0  = (const float*)d_in[2];
  const float* Wih = (const float*)d_in[3];
  const float* Whh = (const float*)d_in[4];
  const float* bih = (const float*)d_in[5];
  const float* bhh = (const float*)d_in[6];
  float* out = (float*)d_out;

  // workspace (~131.4 MB): xpack 64 MB | bf16 ring 67.4 MB | flags 4 KB
  char* w = (char*)d_ws;
  unsigned*       xpack = (unsigned*)w;
  unsigned short* ringb = (unsigned short*)(w + (size_t)T_LEN * HB * 4);
  unsigned*       bar   = (unsigned*)(w + (size_t)T_LEN * HB * 4
                                        + (size_t)2 * RING_SLOTS * HB * 2);

  pack_x<<<(T_LEN * HB) / 4 / 256, 256, 0, stream>>>(x, xpack);
  init_h<<<2 * HB / 4 / 256, 256, 0, stream>>>(h0, ringb, bar);
  lstm_persist<<<NBLK, 512, 0, stream>>>(xpack, c0, Wih, Whh, bih, bhh,
                                         ringb, out, bar);
}

// Round 10
// 9017.522 us; speedup vs baseline: 2.2644x; 2.2644x over previous
//
#include <hip/hip_runtime.h>

#define T_LEN 256
#define B_SZ  64
#define H_SZ  1024
#define G4H   4096
#define HB    (B_SZ * H_SZ)              // 65536
#define NBLK  256
#define RING_SLOTS (T_LEN + 1)           // slot t = h(t); slot T_LEN = h(-1)

typedef __attribute__((ext_vector_type(8))) short short8;
typedef __attribute__((ext_vector_type(4))) float float4_;
typedef __attribute__((ext_vector_type(4))) unsigned int uint4_;
typedef __attribute__((ext_vector_type(8))) unsigned int uint8_;

__device__ __forceinline__ unsigned short bf16_rne(float x) {
  unsigned u = __builtin_bit_cast(unsigned, x);
  unsigned r = u + 0x7FFFu + ((u >> 16) & 1u);
  return (unsigned short)(r >> 16);
}
__device__ __forceinline__ float bf16_to_f32(unsigned short s) {
  unsigned u = ((unsigned)s) << 16;
  return __builtin_bit_cast(float, u);
}

// ---------- prep: x fp32 -> packed split-bf16 (hi | lo<<16) dwords ----------
__global__ __launch_bounds__(256)
void pack_x(const float* __restrict__ src, unsigned* __restrict__ dst) {
  const size_t i = ((size_t)blockIdx.x * 256 + threadIdx.x) * 4;
  float4_ v = *(const float4_*)(src + i);
  uint4_ o;
  #pragma unroll
  for (int j = 0; j < 4; ++j) {
    const unsigned short h = bf16_rne(v[j]);
    const unsigned short l = bf16_rne(v[j] - bf16_to_f32(h));
    o[j] = (unsigned)h | ((unsigned)l << 16);
  }
  *(uint4_*)(dst + i) = o;
}

// ---------- prep: h0 -> bf16 ring slot T_LEN (t = -1) + zero flags ----------
__global__ __launch_bounds__(256)
void init_h(const float* __restrict__ h0, unsigned short* __restrict__ ringb,
            unsigned* __restrict__ bar) {
  if (blockIdx.x == 0) {
    #pragma unroll
    for (int j = 0; j < 4; ++j) bar[threadIdx.x * 4 + j] = 0u;
  }
  const int e0 = (blockIdx.x * 256 + threadIdx.x) * 4;
  #pragma unroll
  for (int j = 0; j < 4; ++j) {
    const int e = e0 + j;                 // [2][B][H] = 131072 elems
    const int l = e >> 16;
    const int rem = e & (HB - 1);
    ringb[((size_t)l * RING_SLOTS + T_LEN) * HB + rem] = bf16_rne(h0[e]);
  }
}

// poll ALL 128 producer flags of a layer in one round (2 loads/lane)
__device__ __forceinline__ void poll_all128(const unsigned* f, unsigned v,
                                            int lane) {
  for (;;) {
    const unsigned a = __hip_atomic_load(f + lane, __ATOMIC_RELAXED,
                                         __HIP_MEMORY_SCOPE_AGENT);
    const unsigned b = __hip_atomic_load(f + 64 + lane, __ATOMIC_RELAXED,
                                         __HIP_MEMORY_SCOPE_AGENT);
    if (__all((int)(a >= v && b >= v))) return;
    __builtin_amdgcn_s_sleep(1);
  }
}
// poll n (<64) contiguous flags; lanes >= n pass vacuously
__device__ __forceinline__ void poll_n(const unsigned* f, int n, unsigned v,
                                       int lane) {
  for (;;) {
    unsigned s = 0xFFFFFFFFu;
    if (lane < n)
      s = __hip_atomic_load(f + lane, __ATOMIC_RELAXED,
                            __HIP_MEMORY_SCOPE_AGENT);
    if (__all((int)(s >= v))) return;
    __builtin_amdgcn_s_sleep(1);
  }
}

// ---------- persistent LSTM: single-critical-wave step ----------
// Per WG (l, cb): wave 0 alone runs the full-K recurrent GEMM (h-weights in
// LDS), assembles gates in-register via 2 shuffle-exchange rounds (ALL array
// indices static; hi8/hi1 selection via value ternaries -> no scratch),
// fuses the elementwise, stores h(t), drains, flags. Waves 1-7 compute the
// x-side for t+1 into a double-buffered LDS gate tile. ONE barrier per step.
__global__ __launch_bounds__(512, 1)
void lstm_persist(const unsigned* __restrict__ xp,     // packed x [T][B][H]
                  const float* __restrict__ c0_in,
                  const float* __restrict__ Wih,       // fp32 [L][4H][H]
                  const float* __restrict__ Whh,
                  const float* __restrict__ bih,
                  const float* __restrict__ bhh,
                  unsigned short* __restrict__ ringb,  // [L][257][B][H] bf16
                  float* __restrict__ out,
                  unsigned* __restrict__ bar)          // [2][128] flags
{
  const int wg   = blockIdx.x;
  const int tid  = threadIdx.x;
  const int lane = tid & 63;
  const int wave = tid >> 6;

  const int layer = wg >> 7;
  const int cb    = wg & 127;
  const int nn    = lane & 15;
  const int quad  = lane >> 4;
  const int hc    = nn & 7;
  const int hi8   = nn >> 3;
  const int hi1   = nn & 1;
  const int hc2   = nn & 6;            // even hcol of this lane's pair

  __shared__ short8 whh[2][32][2][64];   // [pl][kb][nt][lane] = 128 KB
  __shared__ float  xtile[2][64][36];    // 18 KB, dbuf by t&1

  int growA[2];
  #pragma unroll
  for (int nt = 0; nt < 2; ++nt) {
    const int q = nt * 2 + hi8;
    growA[nt] = q * H_SZ + cb * 8 + hc;
  }

  // ---- one-time: Whh -> split-bf16 fragments in LDS (all waves, 4 kb each)
  #pragma unroll
  for (int i = 0; i < 4; ++i) {
    const int kbg = wave * 4 + i;
    #pragma unroll
    for (int nt = 0; nt < 2; ++nt) {
      const float* p = Whh + ((size_t)layer * G4H + growA[nt]) * H_SZ +
                       kbg * 32 + quad * 8;
      short8 hi, lo;
      #pragma unroll
      for (int j = 0; j < 8; ++j) {
        const float v = p[j];
        const unsigned short h = bf16_rne(v);
        hi[j] = (short)h;
        lo[j] = (short)bf16_rne(v - bf16_to_f32(h));
      }
      whh[0][kbg][nt][lane] = hi;
      whh[1][kbg][nt][lane] = lo;
    }
  }

  // ---- one-time: Wih chunk -> registers (waves 1..7; 7-way kb split)
  short8 wx[2][2][5];                    // [pl][nt][i]
  int kbstart = 0, nkb = 0;
  if (wave >= 1) {
    const int sw = wave - 1;
    kbstart = (sw < 4) ? sw * 5 : 20 + (sw - 4) * 4;
    nkb = (sw < 4) ? 5 : 4;
    #pragma unroll
    for (int i = 0; i < 5; ++i) if (i < nkb) {
      #pragma unroll
      for (int nt = 0; nt < 2; ++nt) {
        const float* p = Wih + ((size_t)layer * G4H + growA[nt]) * H_SZ +
                         (kbstart + i) * 32 + quad * 8;
        short8 hi, lo;
        #pragma unroll
        for (int j = 0; j < 8; ++j) {
          const float v = p[j];
          const unsigned short h = bf16_rne(v);
          hi[j] = (short)h;
          lo[j] = (short)bf16_rne(v - bf16_to_f32(h));
        }
        wx[0][nt][i] = hi;
        wx[1][nt][i] = lo;
      }
    }
  }

  // ---- wave-0 elementwise constants
  const int hcol0 = cb * 8 + hc2;
  float bias[2][4];
  #pragma unroll
  for (int s = 0; s < 2; ++s)
    #pragma unroll
    for (int q = 0; q < 4; ++q)
      bias[s][q] = bih[layer * G4H + q * H_SZ + hcol0 + s] +
                   bhh[layer * G4H + q * H_SZ + hcol0 + s];

  unsigned*       slotp = bar + layer * 128 + cb;
  const unsigned* fown  = bar + layer * 128;
  const unsigned* fl0   = bar;
  const unsigned short* ring_own = ringb + (size_t)layer * RING_SLOTS * HB;

  float creg[2][4];
  #pragma unroll
  for (int s = 0; s < 2; ++s)
    #pragma unroll
    for (int r = 0; r < 4; ++r) creg[s][r] = 0.f;

  // ---- shadow x-GEMM + LDS atomic accumulate (waves 1..7)
  auto do_shadow = [&](int tt, int buf) {
    float4_ as[4][2];
    #pragma unroll
    for (int m = 0; m < 4; ++m)
      #pragma unroll
      for (int nt = 0; nt < 2; ++nt)
        as[m][nt] = float4_{0.f, 0.f, 0.f, 0.f};
    if (layer == 0) {
      const unsigned* src = xp + (size_t)tt * HB;
      #pragma unroll
      for (int i = 0; i < 5; ++i) if (i < nkb) {
        const int k0 = (kbstart + i) * 32 + quad * 8;
        #pragma unroll
        for (int m = 0; m < 4; ++m) {
          const uint8_ u = *(const uint8_*)(src + (size_t)(m * 16 + nn) * H_SZ + k0);
          uint4_ h4, l4;
          #pragma unroll
          for (int r = 0; r < 4; ++r) {
            h4[r] = __builtin_amdgcn_perm(u[2 * r + 1], u[2 * r], 0x05040100u);
            l4[r] = __builtin_amdgcn_perm(u[2 * r + 1], u[2 * r], 0x07060302u);
          }
          const short8 ah = __builtin_bit_cast(short8, h4);
          const short8 al = __builtin_bit_cast(short8, l4);
          #pragma unroll
          for (int nt = 0; nt < 2; ++nt) {
            as[m][nt] = __builtin_amdgcn_mfma_f32_16x16x32_bf16(ah, wx[0][nt][i], as[m][nt], 0, 0, 0);
            as[m][nt] = __builtin_amdgcn_mfma_f32_16x16x32_bf16(al, wx[0][nt][i], as[m][nt], 0, 0, 0);
            as[m][nt] = __builtin_amdgcn_mfma_f32_16x16x32_bf16(ah, wx[1][nt][i], as[m][nt], 0, 0, 0);
          }
        }
      }
    } else {
      poll_n(fl0 + kbstart * 4, nkb * 4, (unsigned)(tt + 1), lane);
      asm volatile("" ::: "memory");
      const unsigned short* src = ringb + (size_t)tt * HB;  // layer-0 slot tt
      #pragma unroll
      for (int i = 0; i < 5; ++i) if (i < nkb) {
        const int k0 = (kbstart + i) * 32 + quad * 8;
        #pragma unroll
        for (int m = 0; m < 4; ++m) {
          const short8 a = *(const short8*)(src + (size_t)(m * 16 + nn) * H_SZ + k0);
          #pragma unroll
          for (int nt = 0; nt < 2; ++nt) {
            as[m][nt] = __builtin_amdgcn_mfma_f32_16x16x32_bf16(a, wx[0][nt][i], as[m][nt], 0, 0, 0);
            as[m][nt] = __builtin_amdgcn_mfma_f32_16x16x32_bf16(a, wx[1][nt][i], as[m][nt], 0, 0, 0);
          }
        }
      }
    }
    #pragma unroll
    for (int m = 0; m < 4; ++m)
      #pragma unroll
      for (int nt = 0; nt < 2; ++nt)
        #pragma unroll
        for (int r = 0; r < 4; ++r)
          atomicAdd(&xtile[buf][m * 16 + quad * 4 + r][hc * 4 + nt * 2 + hi8],
                    as[m][nt][r]);
  };

  // ---- prologue: zero xtile, fill xtile[0] with x(0)
  {
    float4_* zb = (float4_*)&xtile[0][0][0];
    #pragma unroll
    for (int i = 0; i < 3; ++i) {
      const int idx = i * 512 + tid;
      if (idx < 2 * 64 * 36 / 4) zb[idx] = float4_{0.f, 0.f, 0.f, 0.f};
    }
  }
  __syncthreads();
  if (wave >= 1) do_shadow(0, 0);
  __syncthreads();

  #pragma unroll 1
  for (int t = 0; t < T_LEN; ++t) {
    if (wave == 0) {
      // ---- wait: all 128 own-layer producers done with step t-1
      if (t > 0) {
        poll_all128(fown, (unsigned)t, lane);
        asm volatile("" ::: "memory");
      }
      // ---- full-K recurrent GEMM, streaming (512 MFMA, one wave)
      const unsigned short* hsrc =
          ring_own + (size_t)(t ? t - 1 : T_LEN) * HB;
      float4_ acc[4][2];
      #pragma unroll
      for (int m = 0; m < 4; ++m)
        #pragma unroll
        for (int nt = 0; nt < 2; ++nt)
          acc[m][nt] = float4_{0.f, 0.f, 0.f, 0.f};
      for (int ck = 0; ck < 8; ++ck) {
        #pragma unroll
        for (int kb = 0; kb < 4; ++kb) {
          const int kbg = ck * 4 + kb;
          const int k0 = kbg * 32 + quad * 8;
          short8 a[4];
          #pragma unroll
          for (int m = 0; m < 4; ++m)
            a[m] = *(const short8*)(hsrc + (size_t)(m * 16 + nn) * H_SZ + k0);
          const short8 bh0 = whh[0][kbg][0][lane];
          const short8 bh1 = whh[0][kbg][1][lane];
          const short8 bl0 = whh[1][kbg][0][lane];
          const short8 bl1 = whh[1][kbg][1][lane];
          #pragma unroll
          for (int m = 0; m < 4; ++m) {
            acc[m][0] = __builtin_amdgcn_mfma_f32_16x16x32_bf16(a[m], bh0, acc[m][0], 0, 0, 0);
            acc[m][0] = __builtin_amdgcn_mfma_f32_16x16x32_bf16(a[m], bl0, acc[m][0], 0, 0, 0);
            acc[m][1] = __builtin_amdgcn_mfma_f32_16x16x32_bf16(a[m], bh1, acc[m][1], 0, 0, 0);
            acc[m][1] = __builtin_amdgcn_mfma_f32_16x16x32_bf16(a[m], bl1, acc[m][1], 0, 0, 0);
          }
        }
      }
      // ---- exchange 1 (xor 8): merge gate split. STATIC indices only;
      // hi8 selection in value space (cndmask), not in subscripts.
      float g[2][4][4];   // [mm][q][r]
      #pragma unroll
      for (int mm = 0; mm < 2; ++mm)
        #pragma unroll
        for (int j = 0; j < 2; ++j)
          #pragma unroll
          for (int r = 0; r < 4; ++r) {
            const float own  = hi8 ? acc[2 + mm][j][r] : acc[mm][j][r];
            const float send = hi8 ? acc[mm][j][r]     : acc[2 + mm][j][r];
            const float rec  = __shfl_xor(send, 8);
            g[mm][2 * j][r]     = hi8 ? rec : own;
            g[mm][2 * j + 1][r] = hi8 ? own : rec;
          }
      // ---- exchange 2 (xor 1): pair adjacent hcols. STATIC indices only.
      float h2[2][4][4];  // [s][q][r]
      #pragma unroll
      for (int q = 0; q < 4; ++q)
        #pragma unroll
        for (int r = 0; r < 4; ++r) {
          const float send = hi1 ? g[0][q][r] : g[1][q][r];
          const float rec  = __shfl_xor(send, 1);
          h2[0][q][r] = hi1 ? rec : g[0][q][r];
          h2[1][q][r] = hi1 ? g[1][q][r] : rec;
        }
      // ---- fused elementwise: 4 batches x 2 hcols per lane
      const int mt = 2 * hi8 + hi1;
      #pragma unroll
      for (int r = 0; r < 4; ++r) {
        const int b = mt * 16 + quad * 4 + r;
        float hn[2];
        #pragma unroll
        for (int s = 0; s < 2; ++s) {
          const float4_ xt = *(const float4_*)&xtile[t & 1][b][(hc2 + s) * 4];
          const float g0 = h2[s][0][r] + xt[0] + bias[s][0];
          const float g1 = h2[s][1][r] + xt[1] + bias[s][1];
          const float g2 = h2[s][2][r] + xt[2] + bias[s][2];
          const float g3 = h2[s][3][r] + xt[3] + bias[s][3];
          const float cprev = (t == 0)
              ? c0_in[(size_t)layer * HB + (size_t)b * H_SZ + hcol0 + s]
              : creg[s][r];
          const float ig = 1.f / (1.f + __expf(-g0));
          const float fg = 1.f / (1.f + __expf(-g1));
          const float gg = tanhf(g2);
          const float og = 1.f / (1.f + __expf(-g3));
          const float cn = fg * cprev + ig * gg;
          hn[s] = og * tanhf(cn);
          creg[s][r] = cn;
        }
        const size_t ridx = ((size_t)layer * RING_SLOTS + t) * HB +
                            (size_t)b * H_SZ + hcol0;      // even -> 4B align
        const unsigned pk = (unsigned)bf16_rne(hn[0]) |
                            ((unsigned)bf16_rne(hn[1]) << 16);
        __hip_atomic_store((unsigned*)(ringb + ridx), pk,
                           __ATOMIC_RELAXED, __HIP_MEMORY_SCOPE_AGENT);
        if (layer == 1 && t == T_LEN - 1) {
          out[(size_t)b * H_SZ + hcol0]     = hn[0];
          out[(size_t)b * H_SZ + hcol0 + 1] = hn[1];
        }
      }
      // ---- re-zero the consumed xtile buffer (for shadow at t+1)
      {
        float4_* zb = (float4_*)&xtile[t & 1][0][0];
        #pragma unroll
        for (int i = 0; i < 9; ++i)
          zb[i * 64 + lane] = float4_{0.f, 0.f, 0.f, 0.f};
      }
      // ---- drain ring stores, then flag
      asm volatile("s_waitcnt vmcnt(0)" ::: "memory");
      if (lane == 0)
        __hip_atomic_store(slotp, (unsigned)(t + 1),
                           __ATOMIC_RELAXED, __HIP_MEMORY_SCOPE_AGENT);
    } else if (t < T_LEN - 1) {
      // ---- shadow: x-side for t+1 into xtile[(t+1)&1]
      do_shadow(t + 1, (t + 1) & 1);
    }
    __syncthreads();   // the ONLY barrier per step
  }
}

extern "C" void kernel_launch(void* const* d_in, const int* in_sizes, int n_in,
                              void* d_out, int out_size, void* d_ws, size_t ws_size,
                              hipStream_t stream) {
  (void)in_sizes; (void)n_in; (void)out_size; (void)ws_size;
  const float* x   = (const float*)d_in[0];
  const float* h0  = (const float*)d_in[1];
  const float* c0  = (const float*)d_in[2];
  const float* Wih = (const float*)d_in[3];
  const float* Whh = (const float*)d_in[4];
  const float* bih = (const float*)d_in[5];
  const float* bhh = (const float*)d_in[6];
  float* out = (float*)d_out;

  // workspace (~131.4 MB): xpack 64 MB | bf16 ring 67.4 MB | flags 4 KB
  char* w = (char*)d_ws;
  unsigned*       xpack = (unsigned*)w;
  unsigned short* ringb = (unsigned short*)(w + (size_t)T_LEN * HB * 4);
  unsigned*       bar   = (unsigned*)(w + (size_t)T_LEN * HB * 4
                                        + (size_t)2 * RING_SLOTS * HB * 2);

  pack_x<<<(T_LEN * HB) / 4 / 256, 256, 0, stream>>>(x, xpack);
  init_h<<<2 * HB / 4 / 256, 256, 0, stream>>>(h0, ringb, bar);
  lstm_persist<<<NBLK, 512, 0, stream>>>(xpack, c0, Wih, Whh, bih, bhh,
                                         ringb, out, bar);
}

// Round 11
// 8448.125 us; speedup vs baseline: 2.4170x; 1.0674x over previous
//
#include <hip/hip_runtime.h>

#define T_LEN 256
#define B_SZ  64
#define H_SZ  1024
#define G4H   4096
#define HB    (B_SZ * H_SZ)              // 65536
#define NBLK  256
#define RING_SLOTS (T_LEN + 1)           // slot t = h(t); slot T_LEN = h(-1)

typedef __attribute__((ext_vector_type(8))) short short8;
typedef __attribute__((ext_vector_type(4))) float float4_;
typedef __attribute__((ext_vector_type(4))) unsigned int uint4_;
typedef __attribute__((ext_vector_type(8))) unsigned int uint8_;

__device__ __forceinline__ unsigned short bf16_rne(float x) {
  unsigned u = __builtin_bit_cast(unsigned, x);
  unsigned r = u + 0x7FFFu + ((u >> 16) & 1u);
  return (unsigned short)(r >> 16);
}
__device__ __forceinline__ float bf16_to_f32(unsigned short s) {
  unsigned u = ((unsigned)s) << 16;
  return __builtin_bit_cast(float, u);
}

// ---------- prep: x fp32 -> packed split-bf16 (hi | lo<<16) dwords ----------
__global__ __launch_bounds__(256)
void pack_x(const float* __restrict__ src, unsigned* __restrict__ dst) {
  const size_t i = ((size_t)blockIdx.x * 256 + threadIdx.x) * 4;
  float4_ v = *(const float4_*)(src + i);
  uint4_ o;
  #pragma unroll
  for (int j = 0; j < 4; ++j) {
    const unsigned short h = bf16_rne(v[j]);
    const unsigned short l = bf16_rne(v[j] - bf16_to_f32(h));
    o[j] = (unsigned)h | ((unsigned)l << 16);
  }
  *(uint4_*)(dst + i) = o;
}

// ---------- prep: h0 -> bf16 ring slot T_LEN (t = -1) + zero flags ----------
__global__ __launch_bounds__(256)
void init_h(const float* __restrict__ h0, unsigned short* __restrict__ ringb,
            unsigned* __restrict__ bar) {
  if (blockIdx.x == 0) {
    #pragma unroll
    for (int j = 0; j < 4; ++j) bar[threadIdx.x * 4 + j] = 0u;
  }
  const int e0 = (blockIdx.x * 256 + threadIdx.x) * 4;
  #pragma unroll
  for (int j = 0; j < 4; ++j) {
    const int e = e0 + j;                 // [2][B][H] = 131072 elems
    const int l = e >> 16;
    const int rem = e & (HB - 1);
    ringb[((size_t)l * RING_SLOTS + T_LEN) * HB + rem] = bf16_rne(h0[e]);
  }
}

// poll ALL 128 producer flags of a layer in one round (2 loads/lane)
__device__ __forceinline__ void poll_all128(const unsigned* f, unsigned v,
                                            int lane) {
  for (;;) {
    const unsigned a = __hip_atomic_load(f + lane, __ATOMIC_RELAXED,
                                         __HIP_MEMORY_SCOPE_AGENT);
    const unsigned b = __hip_atomic_load(f + 64 + lane, __ATOMIC_RELAXED,
                                         __HIP_MEMORY_SCOPE_AGENT);
    if (__all((int)(a >= v && b >= v))) return;
    __builtin_amdgcn_s_sleep(1);
  }
}

// ---------- persistent LSTM: N-split waves, zero-barrier step ----------
// Gate-col packing: n-tile nt col c (0..15) -> gate q = c&3, hcol = cb*8 +
// nt*4 + (c>>2); weight row(c) = q*H + cb*8 + nt*4 + (c>>2). Wave (m = w>>1,
// nt = w&1) computes its complete 16x16 gate tile over FULL K=1024 (Whh in
// LDS), transposes 4x4 in-wave so each lane holds i,f,g,o of one (batch,
// hcol) cell, fuses elementwise, stores h, drains, bumps LDS counter; the
// 8th wave raises the WG flag. x-side runs K-split in shadow into xtile
// (LDS atomics), ordered by a second LDS counter. No __syncthreads in loop.
__global__ __launch_bounds__(512, 1)
void lstm_persist(const unsigned* __restrict__ xp,     // packed x [T][B][H]
                  const float* __restrict__ c0_in,
                  const float* __restrict__ Wih,       // fp32 [L][4H][H]
                  const float* __restrict__ Whh,
                  const float* __restrict__ bih,
                  const float* __restrict__ bhh,
                  unsigned short* __restrict__ ringb,  // [L][257][B][H] bf16
                  float* __restrict__ out,
                  unsigned* __restrict__ bar)          // [2][128] flags
{
  const int wg   = blockIdx.x;
  const int tid  = threadIdx.x;
  const int lane = tid & 63;
  const int wave = tid >> 6;

  const int layer = wg >> 7;
  const int cb    = wg & 127;
  const int nn    = lane & 15;
  const int quad  = lane >> 4;
  const int m     = wave >> 1;         // output batch tile 0..3
  const int nt    = wave & 1;          // output col tile 0..1
  const int g     = lane & 3;          // gate slot pre-transpose
  const int hcg   = (lane >> 2) & 3;   // hcol-in-tile

  __shared__ short8   wh[2][32][2][64];  // [pl][kbg][nt][lane] = 128 KB
  __shared__ float    xtile[2][64][36];  // 18 KB, dbuf
  __shared__ unsigned cnt, xcnt;

  // ---- one-time: Whh -> split-bf16 LDS (wave w stages kbg w*4..w*4+3)
  {
    const int c = lane & 15;
    #pragma unroll
    for (int i = 0; i < 4; ++i) {
      const int kbg = wave * 4 + i;
      #pragma unroll
      for (int ntt = 0; ntt < 2; ++ntt) {
        const int row = (c & 3) * H_SZ + cb * 8 + ntt * 4 + (c >> 2);
        const float* p = Whh + ((size_t)layer * G4H + row) * H_SZ +
                         kbg * 32 + quad * 8;
        short8 hi, lo;
        #pragma unroll
        for (int j = 0; j < 8; ++j) {
          const float v = p[j];
          const unsigned short h = bf16_rne(v);
          hi[j] = (short)h;
          lo[j] = (short)bf16_rne(v - bf16_to_f32(h));
        }
        wh[0][kbg][ntt][lane] = hi;
        wh[1][kbg][ntt][lane] = lo;
      }
    }
  }

  // ---- one-time: Wih K-chunk (kb wave*4..+3, both n-tiles) -> registers
  short8 wx[2][2][4];                    // [pl][ntt][i]
  {
    const int c = lane & 15;
    #pragma unroll
    for (int i = 0; i < 4; ++i)
      #pragma unroll
      for (int ntt = 0; ntt < 2; ++ntt) {
        const int row = (c & 3) * H_SZ + cb * 8 + ntt * 4 + (c >> 2);
        const float* p = Wih + ((size_t)layer * G4H + row) * H_SZ +
                         (wave * 4 + i) * 32 + quad * 8;
        short8 hi, lo;
        #pragma unroll
        for (int j = 0; j < 8; ++j) {
          const float v = p[j];
          const unsigned short h = bf16_rne(v);
          hi[j] = (short)h;
          lo[j] = (short)bf16_rne(v - bf16_to_f32(h));
        }
        wx[0][ntt][i] = hi;
        wx[1][ntt][i] = lo;
      }
  }

  // ---- this lane's output cell
  const int batch = m * 16 + quad * 4 + g;
  const int hcol  = cb * 8 + nt * 4 + hcg;
  float4_ bias4;
  #pragma unroll
  for (int q = 0; q < 4; ++q)
    bias4[q] = bih[layer * G4H + q * H_SZ + hcol] +
               bhh[layer * G4H + q * H_SZ + hcol];

  unsigned*       slotp = bar + layer * 128 + cb;
  const unsigned* fown  = bar + layer * 128;
  const unsigned* fl0   = bar;
  const unsigned short* ring_own = ringb + (size_t)layer * RING_SLOTS * HB;

  // ---- zero xtile + counters
  {
    float* z = &xtile[0][0][0];
    for (int i = tid; i < 2 * 64 * 36; i += 512) z[i] = 0.f;
    if (tid == 0) { cnt = 0u; xcnt = 0u; }
  }
  __syncthreads();   // one-time (staging + zero visible)

  // ---- shadow: x-side gates for step tt into xtile[buf] (K-split, all waves)
  auto do_shadow = [&](int tt, int buf) {
    float4_ as[4][2];
    #pragma unroll
    for (int mm = 0; mm < 4; ++mm)
      #pragma unroll
      for (int ntt = 0; ntt < 2; ++ntt)
        as[mm][ntt] = float4_{0.f, 0.f, 0.f, 0.f};
    if (layer == 0) {
      const unsigned* src = xp + (size_t)tt * HB;
      #pragma unroll
      for (int i = 0; i < 4; ++i) {
        const int k0 = (wave * 4 + i) * 32 + quad * 8;
        #pragma unroll
        for (int mm = 0; mm < 4; ++mm) {
          const uint8_ u = *(const uint8_*)(src + (size_t)(mm * 16 + nn) * H_SZ + k0);
          uint4_ h4, l4;
          #pragma unroll
          for (int r = 0; r < 4; ++r) {
            h4[r] = __builtin_amdgcn_perm(u[2 * r + 1], u[2 * r], 0x05040100u);
            l4[r] = __builtin_amdgcn_perm(u[2 * r + 1], u[2 * r], 0x07060302u);
          }
          const short8 ah = __builtin_bit_cast(short8, h4);
          const short8 al = __builtin_bit_cast(short8, l4);
          #pragma unroll
          for (int ntt = 0; ntt < 2; ++ntt) {
            as[mm][ntt] = __builtin_amdgcn_mfma_f32_16x16x32_bf16(ah, wx[0][ntt][i], as[mm][ntt], 0, 0, 0);
            as[mm][ntt] = __builtin_amdgcn_mfma_f32_16x16x32_bf16(al, wx[0][ntt][i], as[mm][ntt], 0, 0, 0);
            as[mm][ntt] = __builtin_amdgcn_mfma_f32_16x16x32_bf16(ah, wx[1][ntt][i], as[mm][ntt], 0, 0, 0);
          }
        }
      }
    } else {
      poll_all128(fl0, (unsigned)(tt + 1), lane);      // h0(tt) ready
      asm volatile("" ::: "memory");
      const unsigned short* src = ringb + (size_t)tt * HB;  // l0 slot tt
      #pragma unroll
      for (int i = 0; i < 4; ++i) {
        const int k0 = (wave * 4 + i) * 32 + quad * 8;
        #pragma unroll
        for (int mm = 0; mm < 4; ++mm) {
          const short8 a = *(const short8*)(src + (size_t)(mm * 16 + nn) * H_SZ + k0);
          #pragma unroll
          for (int ntt = 0; ntt < 2; ++ntt) {
            as[mm][ntt] = __builtin_amdgcn_mfma_f32_16x16x32_bf16(a, wx[0][ntt][i], as[mm][ntt], 0, 0, 0);
            as[mm][ntt] = __builtin_amdgcn_mfma_f32_16x16x32_bf16(a, wx[1][ntt][i], as[mm][ntt], 0, 0, 0);
          }
        }
      }
    }
    #pragma unroll
    for (int mm = 0; mm < 4; ++mm)
      #pragma unroll
      for (int ntt = 0; ntt < 2; ++ntt)
        #pragma unroll
        for (int r = 0; r < 4; ++r)
          atomicAdd(&xtile[buf][mm * 16 + quad * 4 + r][ntt * 16 + nn],
                    as[mm][ntt][r]);
    asm volatile("s_waitcnt lgkmcnt(0)" ::: "memory");
    if (lane == 0) atomicAdd(&xcnt, 1u);
  };

  do_shadow(0, 0);                       // prologue: x-gates for t=0

  float creg = 0.f;
  volatile unsigned* xcv = &xcnt;

  #pragma unroll 1
  for (int t = 0; t < T_LEN; ++t) {
    // ---- wait: all 128 own-layer producers finished step t-1
    if (t > 0) {
      poll_all128(fown, (unsigned)t, lane);
      asm volatile("" ::: "memory");
    }

    // ---- full-K recurrent GEMM: 32 kbg, 4 independent partial-acc chains
    const unsigned short* hsrc = ring_own + (size_t)(t ? t - 1 : T_LEN) * HB;
    float4_ p[4];
    #pragma unroll
    for (int i = 0; i < 4; ++i) p[i] = float4_{0.f, 0.f, 0.f, 0.f};
    #pragma unroll
    for (int half = 0; half < 2; ++half) {
      short8 a[16];
      #pragma unroll
      for (int i = 0; i < 16; ++i)
        a[i] = *(const short8*)(hsrc + (size_t)(m * 16 + nn) * H_SZ +
                                (half * 16 + i) * 32 + quad * 8);
      #pragma unroll
      for (int i = 0; i < 16; ++i) {
        const int kbg = half * 16 + i;
        const short8 bh = wh[0][kbg][nt][lane];
        const short8 bl = wh[1][kbg][nt][lane];
        p[i & 3] = __builtin_amdgcn_mfma_f32_16x16x32_bf16(a[i], bh, p[i & 3], 0, 0, 0);
        p[i & 3] = __builtin_amdgcn_mfma_f32_16x16x32_bf16(a[i], bl, p[i & 3], 0, 0, 0);
      }
    }
    const float4_ acc = (p[0] + p[1]) + (p[2] + p[3]);

    // ---- in-wave 4x4 transpose (lane groups of 4; static idx, value sel)
    const float a0 = acc[0], a1 = acc[1], a2 = acc[2], a3 = acc[3];
    float s0 = (g & 1) ? a0 : a1;
    float s1 = (g & 1) ? a2 : a3;
    float r0 = __shfl_xor(s0, 1);
    float r1 = __shfl_xor(s1, 1);
    const float b0 = (g & 1) ? r0 : a0;
    const float b1 = (g & 1) ? a1 : r0;
    const float b2 = (g & 1) ? r1 : a2;
    const float b3 = (g & 1) ? a3 : r1;
    s0 = (g & 2) ? b0 : b2;
    s1 = (g & 2) ? b1 : b3;
    r0 = __shfl_xor(s0, 2);
    r1 = __shfl_xor(s1, 2);
    const float q0 = (g & 2) ? r0 : b0;   // gate i of (batch, hcol)
    const float q1 = (g & 2) ? r1 : b1;   // gate f
    const float q2 = (g & 2) ? b2 : r0;   // gate g
    const float q3 = (g & 2) ? b3 : r1;   // gate o

    // ---- wait x-gates for this step (shadow from prev step); read + zero
    const unsigned need = 8u * (unsigned)(t + 1);
    while (*xcv < need) __builtin_amdgcn_s_sleep(1);
    const int xcol = nt * 16 + hcg * 4;
    const float4_ xt = *(const float4_*)&xtile[t & 1][batch][xcol];
    *(float4_*)&xtile[t & 1][batch][xcol] = float4_{0.f, 0.f, 0.f, 0.f};

    // ---- fused elementwise (one cell per lane)
    const float g0 = q0 + xt[0] + bias4[0];
    const float g1 = q1 + xt[1] + bias4[1];
    const float g2 = q2 + xt[2] + bias4[2];
    const float g3 = q3 + xt[3] + bias4[3];
    const float cprev = (t == 0)
        ? c0_in[(size_t)layer * HB + (size_t)batch * H_SZ + hcol] : creg;
    const float ig = 1.f / (1.f + __expf(-g0));
    const float fg = 1.f / (1.f + __expf(-g1));
    const float gg = tanhf(g2);
    const float og = 1.f / (1.f + __expf(-g3));
    const float cn = fg * cprev + ig * gg;
    const float hn = og * tanhf(cn);
    creg = cn;

    // ---- pair hcols (xor 4) -> 4B packed agent store by even-hcg lanes
    const float hnp = __shfl_xor(hn, 4);
    if ((lane & 4) == 0) {
      const unsigned pk = (unsigned)bf16_rne(hn) |
                          ((unsigned)bf16_rne(hnp) << 16);
      __hip_atomic_store(
          (unsigned*)(ringb + ((size_t)layer * RING_SLOTS + t) * HB +
                      (size_t)batch * H_SZ + hcol),
          pk, __ATOMIC_RELAXED, __HIP_MEMORY_SCOPE_AGENT);
    }
    if (layer == 1 && t == T_LEN - 1)
      out[(size_t)batch * H_SZ + hcol] = hn;

    // ---- drain own stores, bump counter; 8th wave raises WG flag
    asm volatile("s_waitcnt vmcnt(0) lgkmcnt(0)" ::: "memory");
    if (lane == 0) {
      const unsigned old = atomicAdd(&cnt, 1u);
      if (old == 8u * (unsigned)t + 7u)
        __hip_atomic_store(slotp, (unsigned)(t + 1),
                           __ATOMIC_RELAXED, __HIP_MEMORY_SCOPE_AGENT);
    }

    // ---- shadow: x-gates for t+1 (off the flag path)
    if (t < T_LEN - 1) do_shadow(t + 1, (t + 1) & 1);
  }
}

extern "C" void kernel_launch(void* const* d_in, const int* in_sizes, int n_in,
                              void* d_out, int out_size, void* d_ws, size_t ws_size,
                              hipStream_t stream) {
  (void)in_sizes; (void)n_in; (void)out_size; (void)ws_size;
  const float* x   = (const float*)d_in[0];
  const float* h0  = (const float*)d_in[1];
  const float* c0  = (const float*)d_in[2];
  const float* Wih = (const float*)d_in[3];
  const float* Whh = (const float*)d_in[4];
  const float* bih = (const float*)d_in[5];
  const float* bhh = (const float*)d_in[6];
  float* out = (float*)d_out;

  // workspace (~131.4 MB): xpack 64 MB | bf16 ring 67.4 MB | flags 4 KB
  char* w = (char*)d_ws;
  unsigned*       xpack = (unsigned*)w;
  unsigned short* ringb = (unsigned short*)(w + (size_t)T_LEN * HB * 4);
  unsigned*       bar   = (unsigned*)(w + (size_t)T_LEN * HB * 4
                                        + (size_t)2 * RING_SLOTS * HB * 2);

  pack_x<<<(T_LEN * HB) / 4 / 256, 256, 0, stream>>>(x, xpack);
  init_h<<<2 * HB / 4 / 256, 256, 0, stream>>>(h0, ringb, bar);
  lstm_persist<<<NBLK, 512, 0, stream>>>(xpack, c0, Wih, Whh, bih, bhh,
                                         ringb, out, bar);
}

// Round 12
// 3802.425 us; speedup vs baseline: 5.3701x; 2.2218x over previous
//
#include <hip/hip_runtime.h>

#define T_LEN 256
#define B_SZ  64
#define H_SZ  1024
#define G4H   4096
#define HB    (B_SZ * H_SZ)              // 65536
#define NBLK  256
#define RING_SLOTS (T_LEN + 1)           // slot t = h(t); slot T_LEN = h(-1)

typedef __attribute__((ext_vector_type(8))) short short8;
typedef __attribute__((ext_vector_type(4))) float float4_;
typedef __attribute__((ext_vector_type(4))) unsigned int uint4_;
typedef __attribute__((ext_vector_type(8))) unsigned int uint8_;

__device__ __forceinline__ unsigned short bf16_rne(float x) {
  unsigned u = __builtin_bit_cast(unsigned, x);
  unsigned r = u + 0x7FFFu + ((u >> 16) & 1u);
  return (unsigned short)(r >> 16);
}
__device__ __forceinline__ float bf16_to_f32(unsigned short s) {
  unsigned u = ((unsigned)s) << 16;
  return __builtin_bit_cast(float, u);
}

// ---------- prep: x fp32 -> packed split-bf16 (hi | lo<<16) dwords ----------
__global__ __launch_bounds__(256)
void pack_x(const float* __restrict__ src, unsigned* __restrict__ dst) {
  const size_t i = ((size_t)blockIdx.x * 256 + threadIdx.x) * 4;
  float4_ v = *(const float4_*)(src + i);
  uint4_ o;
  #pragma unroll
  for (int j = 0; j < 4; ++j) {
    const unsigned short h = bf16_rne(v[j]);
    const unsigned short l = bf16_rne(v[j] - bf16_to_f32(h));
    o[j] = (unsigned)h | ((unsigned)l << 16);
  }
  *(uint4_*)(dst + i) = o;
}

// ---------- prep: h0 -> bf16 ring slot T_LEN (t = -1) + zero sub-flags ------
__global__ __launch_bounds__(256)
void init_h(const float* __restrict__ h0, unsigned short* __restrict__ ringb,
            unsigned* __restrict__ bar) {
  if (blockIdx.x == 0) {
    #pragma unroll
    for (int j = 0; j < 4; ++j) bar[threadIdx.x * 4 + j] = 0u;  // [2][128][4]
  }
  const int e0 = (blockIdx.x * 256 + threadIdx.x) * 4;
  #pragma unroll
  for (int j = 0; j < 4; ++j) {
    const int e = e0 + j;                 // [2][B][H] = 131072 elems
    const int l = e >> 16;
    const int rem = e & (HB - 1);
    ringb[((size_t)l * RING_SLOTS + T_LEN) * HB + rem] = bf16_rne(h0[e]);
  }
}

// poll the 16 sub-flags of batch-group m across this wave's 16 producers
// (dwords chunk[j*4 + m], j=0..15). All lanes poll (dup loads share lines).
__device__ __forceinline__ void poll_mgrp(const unsigned* chunk, int m,
                                          unsigned v, int lane) {
  const unsigned* p = chunk + ((lane & 15) << 2) + m;
  for (;;) {
    const unsigned s = __hip_atomic_load(p, __ATOMIC_RELAXED,
                                         __HIP_MEMORY_SCOPE_AGENT);
    if (__all((int)(s >= v))) return;
    __builtin_amdgcn_s_sleep(1);
  }
}

// poll n (<=128) contiguous sub-flag dwords (layer-1 shadow gate)
__device__ __forceinline__ void poll_range(const unsigned* f, int n,
                                           unsigned v, int lane) {
  for (;;) {
    unsigned a = 0xFFFFFFFFu, b = 0xFFFFFFFFu;
    if (lane < n) a = __hip_atomic_load(f + lane, __ATOMIC_RELAXED,
                                        __HIP_MEMORY_SCOPE_AGENT);
    if (lane + 64 < n) b = __hip_atomic_load(f + lane + 64, __ATOMIC_RELAXED,
                                             __HIP_MEMORY_SCOPE_AGENT);
    if (__all((int)(a >= v && b >= v))) return;
    __builtin_amdgcn_s_sleep(1);
  }
}

// ---------- persistent LSTM: round-8 structure + rebalance + piped poll -----
// h(t) at bf16 ring slot t (write-once, fence-free). Producer WG (l,cb) owns
// hcols [8cb,8cb+8); reducer wave w flags bar[l*512+cb*4+w]=t+1 after its own
// stores drain (batches [16w,16w+16)). Consumer wave v polls per-m-group
// (pipelined: poll grp m -> issue grp-m loads) then MFMAs. x-side K-split is
// REBALANCED: reducer waves 3 kbg, waves 4-7 5 kbg, so the reduce tail
// overlaps shadow work instead of extending the period. ONE barrier per step.
__global__ __launch_bounds__(512, 1)
void lstm_persist(const unsigned* __restrict__ xp,     // packed x [T][B][H]
                  const float* __restrict__ c0_in,
                  const float* __restrict__ Wih,       // fp32 [L][4H][H]
                  const float* __restrict__ Whh,
                  const float* __restrict__ bih,
                  const float* __restrict__ bhh,
                  unsigned short* __restrict__ ringb,  // [L][257][B][H] bf16
                  float* __restrict__ out,
                  unsigned* __restrict__ bar)          // [2][128][4] sub-flags
{
  const int wg   = blockIdx.x;
  const int tid  = threadIdx.x;
  const int lane = tid & 63;
  const int wave = tid >> 6;

  const int layer = wg >> 7;
  const int cb    = wg & 127;
  const int nn    = lane & 15;
  const int quad  = lane >> 4;

  __shared__ float lds[2][8][64][36];   // 144 KB (double-buffered by t&1)

  int growA[2];
  #pragma unroll
  for (int nt = 0; nt < 2; ++nt) {
    const int q = nt * 2 + (nn >> 3);
    growA[nt] = q * H_SZ + cb * 8 + (nn & 7);
  }

  // ---- one-time: Whh -> split-bf16 register fragments (own 4-kbg K-chunk)
  short8 wh[2][2][4];   // [pl][nt][kb]
  #pragma unroll
  for (int nt = 0; nt < 2; ++nt)
    #pragma unroll
    for (int kb = 0; kb < 4; ++kb) {
      const float* p = Whh + ((size_t)layer * G4H + growA[nt]) * H_SZ +
                       wave * 128 + kb * 32 + quad * 8;
      short8 hi, lo;
      #pragma unroll
      for (int j = 0; j < 8; ++j) {
        const float v = p[j];
        const unsigned short h = bf16_rne(v);
        hi[j] = (short)h;
        lo[j] = (short)bf16_rne(v - bf16_to_f32(h));
      }
      wh[0][nt][kb] = hi;
      wh[1][nt][kb] = lo;
    }

  // ---- one-time: Wih rebalanced K-chunk -> registers
  // reducer waves (0-3): 3 kbg; waves 4-7: 5 kbg  (3*4 + 5*4 = 32)
  const int kbstart = (wave < 4) ? wave * 3 : 12 + (wave - 4) * 5;
  const int nkb     = (wave < 4) ? 3 : 5;
  short8 wx[2][2][5];   // [pl][nt][i], i < nkb used
  #pragma unroll
  for (int i = 0; i < 5; ++i) if (i < nkb) {
    #pragma unroll
    for (int nt = 0; nt < 2; ++nt) {
      const float* p = Wih + ((size_t)layer * G4H + growA[nt]) * H_SZ +
                       (kbstart + i) * 32 + quad * 8;
      short8 hi, lo;
      #pragma unroll
      for (int j = 0; j < 8; ++j) {
        const float v = p[j];
        const unsigned short h = bf16_rne(v);
        hi[j] = (short)h;
        lo[j] = (short)bf16_rne(v - bf16_to_f32(h));
      }
      wx[0][nt][i] = hi;
      wx[1][nt][i] = lo;
    }
  }

  // ---- elementwise mapping (waves 0-3): wave owns batches [16w,16w+16)
  const int eb   = wave * 16 + (lane >> 2);   // batch (valid for wave<4)
  const int ec   = (lane & 3) * 2;            // local col pair
  const int ecol = cb * 8 + ec;
  float4_ biasA, biasB;
  #pragma unroll
  for (int q = 0; q < 4; ++q) {
    biasA[q] = bih[layer * G4H + q * H_SZ + ecol] +
               bhh[layer * G4H + q * H_SZ + ecol];
    biasB[q] = bih[layer * G4H + q * H_SZ + ecol + 1] +
               bhh[layer * G4H + q * H_SZ + ecol + 1];
  }

  unsigned*       subflag   = bar + layer * 512 + cb * 4 + wave;  // wave<4
  const unsigned* chunk_own = bar + layer * 512 + wave * 64;      // 64 dwords
  const unsigned* fl0sub    = bar;                                // l0 sub-flags

  const unsigned short* ring_own = ringb + (size_t)layer * RING_SLOTS * HB;
  const unsigned short* ring_l0  = ringb;

  float cA = 0.f, cB = 0.f;
  float4_ acc[4][2];
  #pragma unroll
  for (int m = 0; m < 4; ++m)
    #pragma unroll
    for (int nt = 0; nt < 2; ++nt)
      acc[m][nt] = float4_{0.f, 0.f, 0.f, 0.f};

  // ---- x-side accumulation for step tt into acc (rebalanced K-range)
  auto xside = [&](int tt) {
    if (layer == 0) {
      const unsigned* src = xp + (size_t)tt * HB;
      #pragma unroll
      for (int i = 0; i < 5; ++i) if (i < nkb) {
        const int k0 = (kbstart + i) * 32 + quad * 8;
        #pragma unroll
        for (int m = 0; m < 4; ++m) {
          const uint8_ u = *(const uint8_*)(src + (size_t)(m * 16 + nn) * H_SZ + k0);
          uint4_ h4, l4;
          #pragma unroll
          for (int r = 0; r < 4; ++r) {
            h4[r] = __builtin_amdgcn_perm(u[2 * r + 1], u[2 * r], 0x05040100u);
            l4[r] = __builtin_amdgcn_perm(u[2 * r + 1], u[2 * r], 0x07060302u);
          }
          const short8 ah = __builtin_bit_cast(short8, h4);
          const short8 al = __builtin_bit_cast(short8, l4);
          #pragma unroll
          for (int nt = 0; nt < 2; ++nt) {
            acc[m][nt] = __builtin_amdgcn_mfma_f32_16x16x32_bf16(ah, wx[0][nt][i], acc[m][nt], 0, 0, 0);
            acc[m][nt] = __builtin_amdgcn_mfma_f32_16x16x32_bf16(al, wx[0][nt][i], acc[m][nt], 0, 0, 0);
            acc[m][nt] = __builtin_amdgcn_mfma_f32_16x16x32_bf16(ah, wx[1][nt][i], acc[m][nt], 0, 0, 0);
          }
        }
      }
    } else {
      // gate: l0 producers of cols [kbstart*32, +nkb*32) done with step tt
      poll_range(fl0sub + kbstart * 16, nkb * 16, (unsigned)(tt + 1), lane);
      asm volatile("" ::: "memory");
      const unsigned short* src = ring_l0 + (size_t)tt * HB;   // l0 slot tt
      #pragma unroll
      for (int i = 0; i < 5; ++i) if (i < nkb) {
        const int k0 = (kbstart + i) * 32 + quad * 8;
        #pragma unroll
        for (int m = 0; m < 4; ++m) {
          const short8 a = *(const short8*)(src + (size_t)(m * 16 + nn) * H_SZ + k0);
          #pragma unroll
          for (int nt = 0; nt < 2; ++nt) {
            acc[m][nt] = __builtin_amdgcn_mfma_f32_16x16x32_bf16(a, wx[0][nt][i], acc[m][nt], 0, 0, 0);
            acc[m][nt] = __builtin_amdgcn_mfma_f32_16x16x32_bf16(a, wx[1][nt][i], acc[m][nt], 0, 0, 0);
          }
        }
      }
    }
  };

  // ---- prologue: x-side for t=0
  xside(0);

  #pragma unroll 1
  for (int t = 0; t < T_LEN; ++t) {
    // ---- recurrent half with per-m-group pipelined poll + loads
    {
      const unsigned short* hsrc =
          ring_own + (size_t)(t ? t - 1 : T_LEN) * HB;
      const int kbase = wave * 128 + quad * 8;
      short8 v[16];
      #pragma unroll
      for (int m = 0; m < 4; ++m) {
        if (t > 0) poll_mgrp(chunk_own, m, (unsigned)t, lane);
        #pragma unroll
        for (int kb = 0; kb < 4; ++kb)
          v[m * 4 + kb] = *(const short8*)(hsrc +
                              (size_t)(m * 16 + nn) * H_SZ + kbase + kb * 32);
      }
      asm volatile("" ::: "memory");
      #pragma unroll
      for (int kb = 0; kb < 4; ++kb)
        #pragma unroll
        for (int m = 0; m < 4; ++m)
          #pragma unroll
          for (int nt = 0; nt < 2; ++nt) {
            acc[m][nt] = __builtin_amdgcn_mfma_f32_16x16x32_bf16(v[m * 4 + kb], wh[0][nt][kb], acc[m][nt], 0, 0, 0);
            acc[m][nt] = __builtin_amdgcn_mfma_f32_16x16x32_bf16(v[m * 4 + kb], wh[1][nt][kb], acc[m][nt], 0, 0, 0);
          }
    }

    // ---- partials -> LDS[t&1], gate-permuted col = hcol*4 + gate
    float (*ldsb)[64][36] = lds[t & 1];
    #pragma unroll
    for (int m = 0; m < 4; ++m)
      #pragma unroll
      for (int nt = 0; nt < 2; ++nt)
        #pragma unroll
        for (int r = 0; r < 4; ++r)
          ldsb[wave][m * 16 + quad * 4 + r]
              [((nn & 7) << 2) + nt * 2 + (nn >> 3)] = acc[m][nt][r];
    __syncthreads();   // the ONLY barrier in the step

    if (wave < 4) {
      // ---- reduce over 8 K-waves + fused elementwise (16 batches/wave)
      float4_ gA = biasA, gB = biasB;
      #pragma unroll
      for (int w = 0; w < 8; ++w) {
        gA += *(const float4_*)&ldsb[w][eb][ec * 4];
        gB += *(const float4_*)&ldsb[w][eb][ec * 4 + 4];
      }
      float cpA, cpB;
      if (t == 0) {
        cpA = c0_in[(size_t)layer * HB + (size_t)eb * H_SZ + ecol];
        cpB = c0_in[(size_t)layer * HB + (size_t)eb * H_SZ + ecol + 1];
      } else { cpA = cA; cpB = cB; }
      const float igA = 1.f / (1.f + __expf(-gA[0]));
      const float fgA = 1.f / (1.f + __expf(-gA[1]));
      const float ggA = tanhf(gA[2]);
      const float ogA = 1.f / (1.f + __expf(-gA[3]));
      const float cnA = fgA * cpA + igA * ggA;
      const float hnA = ogA * tanhf(cnA);
      const float igB = 1.f / (1.f + __expf(-gB[0]));
      const float fgB = 1.f / (1.f + __expf(-gB[1]));
      const float ggB = tanhf(gB[2]);
      const float ogB = 1.f / (1.f + __expf(-gB[3]));
      const float cnB = fgB * cpB + igB * ggB;
      const float hnB = ogB * tanhf(cnB);
      cA = cnA; cB = cnB;
      const size_t ridx = ((size_t)layer * RING_SLOTS + t) * HB +
                          (size_t)eb * H_SZ + ecol;   // even -> 4B aligned
      const unsigned pk = (unsigned)bf16_rne(hnA) |
                          ((unsigned)bf16_rne(hnB) << 16);
      __hip_atomic_store((unsigned*)(ringb + ridx), pk,
                         __ATOMIC_RELAXED, __HIP_MEMORY_SCOPE_AGENT);
      if (layer == 1 && t == T_LEN - 1) {
        out[(size_t)eb * H_SZ + ecol]     = hnA;
        out[(size_t)eb * H_SZ + ecol + 1] = hnB;
      }
      // ---- per-wave drain + sub-flag (no barrier, no convoy)
      asm volatile("s_waitcnt vmcnt(0)" ::: "memory");
      if (lane == 0)
        __hip_atomic_store(subflag, (unsigned)(t + 1),
                           __ATOMIC_RELAXED, __HIP_MEMORY_SCOPE_AGENT);
    }

    // ---- shadow: x-side for t+1 (reducers do 3 kbg, waves 4-7 do 5)
    if (t < T_LEN - 1) {
      #pragma unroll
      for (int m = 0; m < 4; ++m)
        #pragma unroll
        for (int nt = 0; nt < 2; ++nt)
          acc[m][nt] = float4_{0.f, 0.f, 0.f, 0.f};
      xside(t + 1);
    }
  }
}

extern "C" void kernel_launch(void* const* d_in, const int* in_sizes, int n_in,
                              void* d_out, int out_size, void* d_ws, size_t ws_size,
                              hipStream_t stream) {
  (void)in_sizes; (void)n_in; (void)out_size; (void)ws_size;
  const float* x   = (const float*)d_in[0];
  const float* h0  = (const float*)d_in[1];
  const float* c0  = (const float*)d_in[2];
  const float* Wih = (const float*)d_in[3];
  const float* Whh = (const float*)d_in[4];
  const float* bih = (const float*)d_in[5];
  const float* bhh = (const float*)d_in[6];
  float* out = (float*)d_out;

  // workspace (~131.4 MB): xpack 64 MB | bf16 ring 67.4 MB | flags 4 KB
  char* w = (char*)d_ws;
  unsigned*       xpack = (unsigned*)w;
  unsigned short* ringb = (unsigned short*)(w + (size_t)T_LEN * HB * 4);
  unsigned*       bar   = (unsigned*)(w + (size_t)T_LEN * HB * 4
                                        + (size_t)2 * RING_SLOTS * HB * 2);

  pack_x<<<(T_LEN * HB) / 4 / 256, 256, 0, stream>>>(x, xpack);
  init_h<<<2 * HB / 4 / 256, 256, 0, stream>>>(h0, ringb, bar);
  lstm_persist<<<NBLK, 512, 0, stream>>>(xpack, c0, Wih, Whh, bih, bhh,
                                         ringb, out, bar);
}